// Round 6
// baseline (939.855 us; speedup 1.0000x reference)
//
#include <hip/hip_runtime.h>
#include <hip/hip_bf16.h>

#define N_NODES 100000
#define N_EDGES 1600000
#define F_IN 256
#define F_OUT 128
#define SCAN_BLOCKS ((N_NODES + 255) / 256)   // 391

#define N_BINS 8
#define BIN_ROWS 12500          // N_NODES / N_BINS
#define L1_BLOCKS 512
#define L1_EDGES (N_EDGES / L1_BLOCKS)   // 3125 exactly
#define L2_CHUNKS 64

typedef __attribute__((ext_vector_type(8))) short short8;
typedef __attribute__((ext_vector_type(4))) float f32x4;
typedef __attribute__((ext_vector_type(2))) float f32x2;
typedef __attribute__((ext_vector_type(2))) unsigned int uint2v;

static __device__ __forceinline__ unsigned short bf16b(float f) {
    __hip_bfloat16 h = __float2bfloat16(f);
    return *reinterpret_cast<unsigned short*>(&h);
}

// ---------- Kernel 1: pack W [256][128] f32 -> bf16 [ks(8)][kk(4)][col(128)][e(8)] ----------
__global__ void wprep_kernel(const float* __restrict__ W, unsigned short* __restrict__ Wsw) {
    int idx = blockIdx.x * 256 + threadIdx.x;   // 0..32767
    int e  = idx & 7;
    int col = (idx >> 3) & 127;
    int kk = (idx >> 10) & 3;
    int ks = idx >> 12;
    int k = ks * 32 + kk * 8 + e;
    Wsw[idx] = bf16b(W[k * 128 + col]);
}

// ---------- Kernel 2: pre = bf16(x @ W) via v_mfma_f32_16x16x32_bf16, no LDS ----------
__global__ void gemm_kernel(const float* __restrict__ x, const unsigned short* __restrict__ Wsw,
                            unsigned short* __restrict__ preb) {
    const int lane = threadIdx.x & 63;
    const int wave = threadIdx.x >> 6;
    const int m0 = blockIdx.x * 64 + wave * 16;
    const int l15 = lane & 15;
    const int kk = lane >> 4;

    int r = m0 + l15;
    if (r > N_NODES - 1) r = N_NODES - 1;   // clamp for load safety; stores guarded
    const float* xr = x + (long)r * F_IN;

    f32x4 acc[8];
#pragma unroll
    for (int i = 0; i < 8; ++i) acc[i] = (f32x4){0.f, 0.f, 0.f, 0.f};

#pragma unroll
    for (int ks = 0; ks < 8; ++ks) {
        float4 xa = *reinterpret_cast<const float4*>(xr + ks * 32 + kk * 8);
        float4 xb = *reinterpret_cast<const float4*>(xr + ks * 32 + kk * 8 + 4);
        short8 a;
        a[0] = (short)bf16b(xa.x); a[1] = (short)bf16b(xa.y); a[2] = (short)bf16b(xa.z); a[3] = (short)bf16b(xa.w);
        a[4] = (short)bf16b(xb.x); a[5] = (short)bf16b(xb.y); a[6] = (short)bf16b(xb.z); a[7] = (short)bf16b(xb.w);
        const short8* wv = reinterpret_cast<const short8*>(Wsw) + ((ks * 4 + kk) * 128 + l15);
#pragma unroll
        for (int nf = 0; nf < 8; ++nf) {
            short8 b = wv[nf * 16];
            acc[nf] = __builtin_amdgcn_mfma_f32_16x16x32_bf16(a, b, acc[nf], 0, 0, 0);
        }
    }

    // C/D layout: col = lane&15, row = (lane>>4)*4 + reg
    const int rbase = m0 + (lane >> 4) * 4;
#pragma unroll
    for (int nf = 0; nf < 8; ++nf) {
        int cc = nf * 16 + l15;
#pragma unroll
        for (int reg = 0; reg < 4; ++reg) {
            int rr = rbase + reg;
            if (rr < N_NODES) preb[(long)rr * F_OUT + cc] = bf16b(acc[nf][reg]);
        }
    }
}

// ---------- passA: per-(bin, xcd-proxy) edge counts + fused degree histogram ----------
__global__ __launch_bounds__(256) void passA_kernel(const int* __restrict__ row,
                                                    int* __restrict__ deg,
                                                    int* __restrict__ cnt64) {
    __shared__ int h[N_BINS];
    if (threadIdx.x < N_BINS) h[threadIdx.x] = 0;
    __syncthreads();
    const int g = blockIdx.x;
    const int base = g * L1_EDGES;
    for (int i = threadIdx.x; i < L1_EDGES; i += 256) {
        int r = __builtin_nontemporal_load(row + base + i);
        atomicAdd(&deg[r], 1);
        atomicAdd(&h[r / BIN_ROWS], 1);
    }
    __syncthreads();
    if (threadIdx.x < N_BINS)
        atomicAdd(&cnt64[threadIdx.x * N_BINS + (g & 7)], h[threadIdx.x]);
}

// ---------- scan64: exclusive scan of the 64 (bin-major) counts ----------
__global__ void scan64_kernel(const int* __restrict__ cnt64, int* __restrict__ off65,
                              int* __restrict__ cursor64) {
    __shared__ int tmp[64];
    int t = threadIdx.x;             // 64 threads
    int v = cnt64[t];
    tmp[t] = v;
    __syncthreads();
#pragma unroll
    for (int o = 1; o < 64; o <<= 1) {
        int u = (t >= o) ? tmp[t - o] : 0;
        __syncthreads();
        tmp[t] += u;
        __syncthreads();
    }
    int excl = tmp[t] - v;
    off65[t] = excl;
    cursor64[t] = excl;
    if (t == 63) off65[64] = tmp[63];
}

// ---------- passB: append edges to (bin, blockIdx&7) regions; wave-aggregated cursors ----------
// Region writers all live on one XCD (round-robin block dispatch) and regions are
// append-only -> write frontier = 64 moving lines -> full-line writebacks.
__global__ __launch_bounds__(256) void passB_kernel(const int* __restrict__ row,
                                                    const int* __restrict__ col,
                                                    const float* __restrict__ vals,
                                                    int* __restrict__ cursor64,
                                                    unsigned* __restrict__ packed,
                                                    unsigned short* __restrict__ valh) {
    const int g = blockIdx.x;
    const int base = g * L1_EDGES;
    const int xcd = g & 7;
    const int lane = threadIdx.x & 63;
    for (int i = threadIdx.x; i < L1_EDGES; i += 256) {
        int e = base + i;
        int r = __builtin_nontemporal_load(row + e);
        int c = __builtin_nontemporal_load(col + e);
        float v = __builtin_nontemporal_load(vals + e);
        int bin = r / BIN_ROWS;
        int lr = r - bin * BIN_ROWS;
        int pos = 0;
#pragma unroll
        for (int b = 0; b < N_BINS; ++b) {
            unsigned long long m = __ballot(bin == b);
            if (bin == b) {
                unsigned long long lower = m & ((1ull << lane) - 1ull);
                int rank = __popcll(lower);
                int basep = 0;
                if (rank == 0) basep = atomicAdd(&cursor64[b * N_BINS + xcd], (int)__popcll(m));
                basep = __shfl(basep, (int)(__ffsll((long long)m) - 1));
                pos = basep + rank;
            }
        }
        packed[pos] = (unsigned)c | ((unsigned)lr << 17);
        valh[pos] = bf16b(v);
    }
}

// ---------- csr_place: per-bin placement into final CSR slots ----------
// bin = blockIdx&7 -> all of a bin's blocks on one XCD; dirty CSR region (1.6MB)
// sits in that L2 with only the bin's own 1.6MB stream (NT) flowing through.
__global__ __launch_bounds__(256) void csr_place_kernel(const unsigned* __restrict__ packed,
                                                        const unsigned short* __restrict__ valh,
                                                        const int* __restrict__ off65,
                                                        int* __restrict__ csr_cursor,
                                                        uint2v* __restrict__ edges) {
    const int bin = blockIdx.x & 7;
    const int chunk = blockIdx.x >> 3;
    const int lo = off65[bin * N_BINS];
    const int hi = off65[bin * N_BINS + N_BINS];   // contiguous: next bin's start (or off65[64])
    const int len = hi - lo;
    const int clen = (len + L2_CHUNKS - 1) / L2_CHUNKS;
    const int s = lo + chunk * clen;
    const int e_end = min(s + clen, hi);
    const int rbase = bin * BIN_ROWS;
    for (int i = s + (int)threadIdx.x; i < e_end; i += 256) {
        unsigned p = __builtin_nontemporal_load(packed + i);
        unsigned short vh = __builtin_nontemporal_load(valh + i);
        int c = (int)(p & 0x1FFFFu);
        int r = rbase + (int)(p >> 17);
        int pos = atomicAdd(&csr_cursor[r], 1);
        float v = __uint_as_float(((unsigned)vh) << 16);
        edges[pos] = (uint2v){(unsigned)c, __float_as_uint(v)};
    }
}

// ---------- row_start scans (unchanged) ----------
__global__ void scan_block_kernel(const int* __restrict__ deg, int* __restrict__ row_start,
                                  int* __restrict__ bsums) {
    __shared__ int tmp[256];
    int t = threadIdx.x;
    int i = blockIdx.x * 256 + t;
    int d = (i < N_NODES) ? deg[i] : 0;
    tmp[t] = d;
    __syncthreads();
#pragma unroll
    for (int o = 1; o < 256; o <<= 1) {
        int v = (t >= o) ? tmp[t - o] : 0;
        __syncthreads();
        tmp[t] += v;
        __syncthreads();
    }
    if (i < N_NODES) row_start[i] = tmp[t] - d;
    if (t == 255) bsums[blockIdx.x] = tmp[255];
}

__global__ void scan_bsums_kernel(int* __restrict__ bsums) {
    __shared__ int tmp[512];
    int t = threadIdx.x;
    int v = (t < SCAN_BLOCKS) ? bsums[t] : 0;
    tmp[t] = v;
    __syncthreads();
#pragma unroll
    for (int o = 1; o < 512; o <<= 1) {
        int u = (t >= o) ? tmp[t - o] : 0;
        __syncthreads();
        tmp[t] += u;
        __syncthreads();
    }
    bsums[t] = tmp[t] - v;
}

__global__ void scan_add_kernel(int* __restrict__ row_start, const int* __restrict__ bsums,
                                int* __restrict__ cursor) {
    int i = blockIdx.x * 256 + threadIdx.x;
    if (i < N_NODES) {
        int v = row_start[i] + bsums[blockIdx.x];
        row_start[i] = v;
        cursor[i] = v;
        if (i == N_NODES - 1) row_start[N_NODES] = N_EDGES;
    }
}

// ---------- spmm: readlane edge broadcast + 8-deep unconditional gather MLP ----------
__global__ __launch_bounds__(256) void spmm_csr_kernel(
    const unsigned short* __restrict__ preb, const int* __restrict__ row_start,
    const uint2v* __restrict__ edges, const float* __restrict__ bias,
    float* __restrict__ out) {
    const int lane = threadIdx.x & 63;
    const int r = blockIdx.x * 4 + (threadIdx.x >> 6);
    const int s = row_start[r];
    const int t = row_start[r + 1];
    const int n = t - s;
    float a0 = 0.f, a1 = 0.f;

    // One coalesced load grabs up to 64 edges of this row; padded lanes carry
    // {col=0, val=0} so the inner loop needs no bounds checks (0-contribution).
    uint2v ev = (uint2v){0u, 0u};
    if (lane < n) ev = edges[s + lane];
    const int nn = n < 64 ? n : 64;
    for (int j0 = 0; j0 < nn; j0 += 8) {
#pragma unroll
        for (int jj = 0; jj < 8; ++jj) {
            int j = j0 + jj;
            unsigned c = (unsigned)__builtin_amdgcn_readlane((int)ev.x, j);
            unsigned vb = (unsigned)__builtin_amdgcn_readlane((int)ev.y, j);
            unsigned g = *reinterpret_cast<const unsigned*>(preb + (size_t)c * F_OUT + lane * 2);
            float v = __uint_as_float(vb);
            a0 += v * __uint_as_float(g << 16);
            a1 += v * __uint_as_float(g & 0xFFFF0000u);
        }
    }
    // Rare n > 64 fallback (cached broadcast loads).
    for (int e = s + 64; e < t; ++e) {
        uint2v cv = edges[e];
        float v = __uint_as_float(cv.y);
        unsigned g = *reinterpret_cast<const unsigned*>(preb + (size_t)cv.x * F_OUT + lane * 2);
        a0 += v * __uint_as_float(g << 16);
        a1 += v * __uint_as_float(g & 0xFFFF0000u);
    }

    float2 bb = *reinterpret_cast<const float2*>(bias + lane * 2);
    f32x2 o;
    o.x = fmaxf(a0 + bb.x, 0.f);
    o.y = fmaxf(a1 + bb.y, 0.f);
    __builtin_nontemporal_store(o, reinterpret_cast<f32x2*>(out + (size_t)r * F_OUT + lane * 2));
}

extern "C" void kernel_launch(void* const* d_in, const int* in_sizes, int n_in,
                              void* d_out, int out_size, void* d_ws, size_t ws_size,
                              hipStream_t stream) {
    const float* x    = (const float*)d_in[0];
    const float* W    = (const float*)d_in[1];
    const float* b    = (const float*)d_in[2];
    const float* vals = (const float*)d_in[3];
    const int*   row  = (const int*)d_in[4];
    const int*   col  = (const int*)d_in[5];
    float* out = (float*)d_out;

    // Workspace layout, total 48,870,656 B (<= 51.3 MB proven available in R1):
    char* ws = (char*)d_ws;
    unsigned short* preb      = (unsigned short*)(ws);                 // 25,600,000
    unsigned short* Wsw       = (unsigned short*)(ws + 25600000);      //     65,536
    int*            row_start = (int*)(ws + 25665536);                 //    400,016
    int*            cursor    = (int*)(ws + 26065552);                 //    400,000 (deg, then csr cursors)
    int*            bsums     = (int*)(ws + 26465552);                 //      4,096
    int*            cnt64     = (int*)(ws + 26469648);                 //        256
    int*            off65     = (int*)(ws + 26469904);                 //        384
    int*            cursor64  = (int*)(ws + 26470288);                 //        256 (+pad to 26,470,656)
    uint2v*         edges     = (uint2v*)(ws + 26470656);              // 12,800,000
    unsigned*       packed    = (unsigned*)(ws + 39270656);            //  6,400,000
    unsigned short* valh      = (unsigned short*)(ws + 45670656);      //  3,200,000

    // Zero deg + bsums + cnt64 (+off65/cursor64, recomputed anyway) in one memset.
    (void)hipMemsetAsync(cursor, 0, 26470656 - 26065552, stream);

    wprep_kernel<<<128, 256, 0, stream>>>(W, Wsw);
    gemm_kernel<<<(N_NODES + 63) / 64, 256, 0, stream>>>(x, Wsw, preb);

    passA_kernel<<<L1_BLOCKS, 256, 0, stream>>>(row, cursor, cnt64);
    scan64_kernel<<<1, 64, 0, stream>>>(cnt64, off65, cursor64);
    passB_kernel<<<L1_BLOCKS, 256, 0, stream>>>(row, col, vals, cursor64, packed, valh);

    scan_block_kernel<<<SCAN_BLOCKS, 256, 0, stream>>>(cursor, row_start, bsums);
    scan_bsums_kernel<<<1, 512, 0, stream>>>(bsums);
    scan_add_kernel<<<SCAN_BLOCKS, 256, 0, stream>>>(row_start, bsums, cursor);

    csr_place_kernel<<<N_BINS * L2_CHUNKS, 256, 0, stream>>>(packed, valh, off65, cursor, edges);

    spmm_csr_kernel<<<N_NODES / 4, 256, 0, stream>>>(preb, row_start, edges, b, out);
}

// Round 7
// 256.540 us; speedup vs baseline: 3.6636x; 3.6636x over previous
//
#include <hip/hip_runtime.h>
#include <hip/hip_bf16.h>

#define N_NODES 100000
#define N_EDGES 1600000
#define F_IN 256
#define F_OUT 128
#define SCAN_BLOCKS ((N_NODES + 255) / 256)   // 391

#define N_BINS 8
#define BIN_ROWS 12500          // N_NODES / N_BINS
#define L1_BLOCKS 512
#define L1_EDGES (N_EDGES / L1_BLOCKS)   // 3125 exactly
#define L2_CHUNKS 64

typedef __attribute__((ext_vector_type(8))) short short8;
typedef __attribute__((ext_vector_type(4))) float f32x4;
typedef __attribute__((ext_vector_type(2))) float f32x2;
typedef __attribute__((ext_vector_type(2))) unsigned int uint2v;

static __device__ __forceinline__ unsigned short bf16b(float f) {
    __hip_bfloat16 h = __float2bfloat16(f);
    return *reinterpret_cast<unsigned short*>(&h);
}

// ---------- Kernel 1: pack W [256][128] f32 -> bf16 [ks(8)][kk(4)][col(128)][e(8)] ----------
__global__ void wprep_kernel(const float* __restrict__ W, unsigned short* __restrict__ Wsw) {
    int idx = blockIdx.x * 256 + threadIdx.x;   // 0..32767
    int e  = idx & 7;
    int col = (idx >> 3) & 127;
    int kk = (idx >> 10) & 3;
    int ks = idx >> 12;
    int k = ks * 32 + kk * 8 + e;
    Wsw[idx] = bf16b(W[k * 128 + col]);
}

// ---------- Kernel 2: pre = bf16(x @ W) via v_mfma_f32_16x16x32_bf16, no LDS ----------
__global__ void gemm_kernel(const float* __restrict__ x, const unsigned short* __restrict__ Wsw,
                            unsigned short* __restrict__ preb) {
    const int lane = threadIdx.x & 63;
    const int wave = threadIdx.x >> 6;
    const int m0 = blockIdx.x * 64 + wave * 16;
    const int l15 = lane & 15;
    const int kk = lane >> 4;

    int r = m0 + l15;
    if (r > N_NODES - 1) r = N_NODES - 1;   // clamp for load safety; stores guarded
    const float* xr = x + (long)r * F_IN;

    f32x4 acc[8];
#pragma unroll
    for (int i = 0; i < 8; ++i) acc[i] = (f32x4){0.f, 0.f, 0.f, 0.f};

#pragma unroll
    for (int ks = 0; ks < 8; ++ks) {
        float4 xa = *reinterpret_cast<const float4*>(xr + ks * 32 + kk * 8);
        float4 xb = *reinterpret_cast<const float4*>(xr + ks * 32 + kk * 8 + 4);
        short8 a;
        a[0] = (short)bf16b(xa.x); a[1] = (short)bf16b(xa.y); a[2] = (short)bf16b(xa.z); a[3] = (short)bf16b(xa.w);
        a[4] = (short)bf16b(xb.x); a[5] = (short)bf16b(xb.y); a[6] = (short)bf16b(xb.z); a[7] = (short)bf16b(xb.w);
        const short8* wv = reinterpret_cast<const short8*>(Wsw) + ((ks * 4 + kk) * 128 + l15);
#pragma unroll
        for (int nf = 0; nf < 8; ++nf) {
            short8 b = wv[nf * 16];
            acc[nf] = __builtin_amdgcn_mfma_f32_16x16x32_bf16(a, b, acc[nf], 0, 0, 0);
        }
    }

    // C/D layout: col = lane&15, row = (lane>>4)*4 + reg
    const int rbase = m0 + (lane >> 4) * 4;
#pragma unroll
    for (int nf = 0; nf < 8; ++nf) {
        int cc = nf * 16 + l15;
#pragma unroll
        for (int reg = 0; reg < 4; ++reg) {
            int rr = rbase + reg;
            if (rr < N_NODES) preb[(long)rr * F_OUT + cc] = bf16b(acc[nf][reg]);
        }
    }
}

// ---------- passA: per-(bin, block) counts (NO global atomics on counters) + degree hist ----------
__global__ __launch_bounds__(256) void passA_kernel(const int* __restrict__ row,
                                                    int* __restrict__ deg,
                                                    int* __restrict__ cnt) {
    __shared__ int h[N_BINS];
    if (threadIdx.x < N_BINS) h[threadIdx.x] = 0;
    __syncthreads();
    const int g = blockIdx.x;
    const int base = g * L1_EDGES;
    for (int i = threadIdx.x; i < L1_EDGES; i += 256) {
        int r = __builtin_nontemporal_load(row + base + i);
        atomicAdd(&deg[r], 1);                       // 100k addresses: fine
        atomicAdd(&h[r / BIN_ROWS], 1);              // LDS
    }
    __syncthreads();
    if (threadIdx.x < N_BINS)
        cnt[threadIdx.x * L1_BLOCKS + g] = h[threadIdx.x];   // bin-major: regions = [bin][block]
}

// ---------- scan4096: exclusive scan of cnt[8][512] -> off[4097] ----------
__global__ void scan4096_kernel(const int* __restrict__ cnt, int* __restrict__ off) {
    __shared__ int tmp[1024];
    int t = threadIdx.x;                 // 1024 threads
    int4 v = reinterpret_cast<const int4*>(cnt)[t];
    int s1 = v.x, s2 = s1 + v.y, s3 = s2 + v.z, s4 = s3 + v.w;
    tmp[t] = s4;
    __syncthreads();
#pragma unroll
    for (int o = 1; o < 1024; o <<= 1) {
        int u = (t >= o) ? tmp[t - o] : 0;
        __syncthreads();
        tmp[t] += u;
        __syncthreads();
    }
    int base = tmp[t] - s4;              // exclusive
    off[4 * t + 0] = base;
    off[4 * t + 1] = base + s1;
    off[4 * t + 2] = base + s2;
    off[4 * t + 3] = base + s3;
    if (t == 1023) off[4096] = tmp[1023];
}

// ---------- passB: append to pre-reserved (bin, block) sub-regions; LDS-only cursors ----------
__global__ __launch_bounds__(256) void passB_kernel(const int* __restrict__ row,
                                                    const int* __restrict__ col,
                                                    const float* __restrict__ vals,
                                                    const int* __restrict__ off,
                                                    unsigned* __restrict__ packed,
                                                    unsigned short* __restrict__ valh) {
    __shared__ int cur[N_BINS];
    const int g = blockIdx.x;
    if (threadIdx.x < N_BINS) cur[threadIdx.x] = off[threadIdx.x * L1_BLOCKS + g];
    __syncthreads();
    const int base = g * L1_EDGES;
    for (int i = threadIdx.x; i < L1_EDGES; i += 256) {
        int e = base + i;
        int r = __builtin_nontemporal_load(row + e);
        int c = __builtin_nontemporal_load(col + e);
        float v = __builtin_nontemporal_load(vals + e);
        int bin = r / BIN_ROWS;
        int lr = r - bin * BIN_ROWS;
        int pos = atomicAdd(&cur[bin], 1);           // LDS atomic: block-local, ~cycles
        packed[pos] = (unsigned)c | ((unsigned)lr << 17);
        valh[pos] = bf16b(v);
    }
}

// ---------- csr_place: per-bin placement into final CSR slots ----------
// bin = blockIdx&7 -> all of a bin's blocks on one XCD; dirty CSR region (1.6MB)
// sits in that L2 with only the bin's own 2.4MB stream (NT) flowing through.
__global__ __launch_bounds__(256) void csr_place_kernel(const unsigned* __restrict__ packed,
                                                        const unsigned short* __restrict__ valh,
                                                        const int* __restrict__ off,
                                                        int* __restrict__ csr_cursor,
                                                        uint2v* __restrict__ edges) {
    const int bin = blockIdx.x & 7;
    const int chunk = blockIdx.x >> 3;
    const int lo = off[bin * L1_BLOCKS];
    const int hi = off[bin * L1_BLOCKS + L1_BLOCKS];   // next bin's start (off[4096] for bin 7)
    const int len = hi - lo;
    const int clen = (len + L2_CHUNKS - 1) / L2_CHUNKS;
    const int s = lo + chunk * clen;
    const int e_end = min(s + clen, hi);
    const int rbase = bin * BIN_ROWS;
    for (int i = s + (int)threadIdx.x; i < e_end; i += 256) {
        unsigned p = __builtin_nontemporal_load(packed + i);
        unsigned short vh = __builtin_nontemporal_load(valh + i);
        int c = (int)(p & 0x1FFFFu);
        int r = rbase + (int)(p >> 17);
        int pos = atomicAdd(&csr_cursor[r], 1);
        float v = __uint_as_float(((unsigned)vh) << 16);
        edges[pos] = (uint2v){(unsigned)c, __float_as_uint(v)};
    }
}

// ---------- row_start scans (unchanged) ----------
__global__ void scan_block_kernel(const int* __restrict__ deg, int* __restrict__ row_start,
                                  int* __restrict__ bsums) {
    __shared__ int tmp[256];
    int t = threadIdx.x;
    int i = blockIdx.x * 256 + t;
    int d = (i < N_NODES) ? deg[i] : 0;
    tmp[t] = d;
    __syncthreads();
#pragma unroll
    for (int o = 1; o < 256; o <<= 1) {
        int v = (t >= o) ? tmp[t - o] : 0;
        __syncthreads();
        tmp[t] += v;
        __syncthreads();
    }
    if (i < N_NODES) row_start[i] = tmp[t] - d;
    if (t == 255) bsums[blockIdx.x] = tmp[255];
}

__global__ void scan_bsums_kernel(int* __restrict__ bsums) {
    __shared__ int tmp[512];
    int t = threadIdx.x;
    int v = (t < SCAN_BLOCKS) ? bsums[t] : 0;
    tmp[t] = v;
    __syncthreads();
#pragma unroll
    for (int o = 1; o < 512; o <<= 1) {
        int u = (t >= o) ? tmp[t - o] : 0;
        __syncthreads();
        tmp[t] += u;
        __syncthreads();
    }
    bsums[t] = tmp[t] - v;
}

__global__ void scan_add_kernel(int* __restrict__ row_start, const int* __restrict__ bsums,
                                int* __restrict__ cursor) {
    int i = blockIdx.x * 256 + threadIdx.x;
    if (i < N_NODES) {
        int v = row_start[i] + bsums[blockIdx.x];
        row_start[i] = v;
        cursor[i] = v;
        if (i == N_NODES - 1) row_start[N_NODES] = N_EDGES;
    }
}

// ---------- spmm: readlane edge broadcast + 8-deep unconditional gather MLP ----------
__global__ __launch_bounds__(256) void spmm_csr_kernel(
    const unsigned short* __restrict__ preb, const int* __restrict__ row_start,
    const uint2v* __restrict__ edges, const float* __restrict__ bias,
    float* __restrict__ out) {
    const int lane = threadIdx.x & 63;
    const int r = blockIdx.x * 4 + (threadIdx.x >> 6);
    const int s = row_start[r];
    const int t = row_start[r + 1];
    const int n = t - s;
    float a0 = 0.f, a1 = 0.f;

    // One coalesced load grabs up to 64 edges of this row; padded lanes carry
    // {col=0, val=0} so the inner loop needs no bounds checks (0-contribution).
    uint2v ev = (uint2v){0u, 0u};
    if (lane < n) ev = edges[s + lane];
    const int nn = n < 64 ? n : 64;
    for (int j0 = 0; j0 < nn; j0 += 8) {
#pragma unroll
        for (int jj = 0; jj < 8; ++jj) {
            int j = j0 + jj;
            unsigned c = (unsigned)__builtin_amdgcn_readlane((int)ev.x, j);
            unsigned vb = (unsigned)__builtin_amdgcn_readlane((int)ev.y, j);
            unsigned g = *reinterpret_cast<const unsigned*>(preb + (size_t)c * F_OUT + lane * 2);
            float v = __uint_as_float(vb);
            a0 += v * __uint_as_float(g << 16);
            a1 += v * __uint_as_float(g & 0xFFFF0000u);
        }
    }
    // Rare n > 64 fallback (cached broadcast loads).
    for (int e = s + 64; e < t; ++e) {
        uint2v cv = edges[e];
        float v = __uint_as_float(cv.y);
        unsigned g = *reinterpret_cast<const unsigned*>(preb + (size_t)cv.x * F_OUT + lane * 2);
        a0 += v * __uint_as_float(g << 16);
        a1 += v * __uint_as_float(g & 0xFFFF0000u);
    }

    float2 bb = *reinterpret_cast<const float2*>(bias + lane * 2);
    f32x2 o;
    o.x = fmaxf(a0 + bb.x, 0.f);
    o.y = fmaxf(a1 + bb.y, 0.f);
    __builtin_nontemporal_store(o, reinterpret_cast<f32x2*>(out + (size_t)r * F_OUT + lane * 2));
}

extern "C" void kernel_launch(void* const* d_in, const int* in_sizes, int n_in,
                              void* d_out, int out_size, void* d_ws, size_t ws_size,
                              hipStream_t stream) {
    const float* x    = (const float*)d_in[0];
    const float* W    = (const float*)d_in[1];
    const float* b    = (const float*)d_in[2];
    const float* vals = (const float*)d_in[3];
    const int*   row  = (const int*)d_in[4];
    const int*   col  = (const int*)d_in[5];
    float* out = (float*)d_out;

    // Workspace layout, total 48,902,528 B (<= 51.3 MB proven available in R1):
    char* ws = (char*)d_ws;
    unsigned short* preb      = (unsigned short*)(ws);                 // 25,600,000
    unsigned short* Wsw       = (unsigned short*)(ws + 25600000);      //     65,536
    int*            row_start = (int*)(ws + 25665536);                 //    400,016
    int*            cursor    = (int*)(ws + 26065552);                 //    400,000 (deg, then csr cursors)
    int*            bsums     = (int*)(ws + 26465552);                 //      4,096
    int*            cnt4096   = (int*)(ws + 26469648);                 //     16,384
    int*            off4097   = (int*)(ws + 26486032);                 //     16,388 (+pad to 26,502,528)
    uint2v*         edges     = (uint2v*)(ws + 26502528);              // 12,800,000
    unsigned*       packed    = (unsigned*)(ws + 39302528);            //  6,400,000
    unsigned short* valh      = (unsigned short*)(ws + 45702528);      //  3,200,000

    // Zero deg (cursor buffer); cnt4096/off4097 are fully overwritten each call.
    (void)hipMemsetAsync(cursor, 0, 400000, stream);

    wprep_kernel<<<128, 256, 0, stream>>>(W, Wsw);
    gemm_kernel<<<(N_NODES + 63) / 64, 256, 0, stream>>>(x, Wsw, preb);

    passA_kernel<<<L1_BLOCKS, 256, 0, stream>>>(row, cursor, cnt4096);
    scan4096_kernel<<<1, 1024, 0, stream>>>(cnt4096, off4097);
    passB_kernel<<<L1_BLOCKS, 256, 0, stream>>>(row, col, vals, off4097, packed, valh);

    scan_block_kernel<<<SCAN_BLOCKS, 256, 0, stream>>>(cursor, row_start, bsums);
    scan_bsums_kernel<<<1, 512, 0, stream>>>(bsums);
    scan_add_kernel<<<SCAN_BLOCKS, 256, 0, stream>>>(row_start, bsums, cursor);

    csr_place_kernel<<<N_BINS * L2_CHUNKS, 256, 0, stream>>>(packed, valh, off4097, cursor, edges);

    spmm_csr_kernel<<<N_NODES / 4, 256, 0, stream>>>(preb, row_start, edges, b, out);
}

// Round 8
// 232.583 us; speedup vs baseline: 4.0410x; 1.1030x over previous
//
#include <hip/hip_runtime.h>
#include <hip/hip_bf16.h>

#define N_NODES 100000
#define N_EDGES 1600000
#define F_IN 256
#define F_OUT 128
#define SCAN_BLOCKS ((N_NODES + 255) / 256)   // 391

#define N_BINS 128
#define RPB 782                  // rows per bin: 128*782 = 100096 >= 100000
#define L1_BLOCKS 256
#define L1_THREADS 512
#define L1_EDGES (N_EDGES / L1_BLOCKS)   // 6250 exactly
#define CNT_SIZE (N_BINS * L1_BLOCKS)    // 32768

typedef __attribute__((ext_vector_type(8))) short short8;
typedef __attribute__((ext_vector_type(4))) float f32x4;
typedef __attribute__((ext_vector_type(2))) float f32x2;
typedef __attribute__((ext_vector_type(2))) unsigned int uint2v;

static __device__ __forceinline__ unsigned short bf16b(float f) {
    __hip_bfloat16 h = __float2bfloat16(f);
    return *reinterpret_cast<unsigned short*>(&h);
}

// ---------- Kernel 1: pack W [256][128] f32 -> bf16 [ks(8)][kk(4)][col(128)][e(8)] ----------
__global__ void wprep_kernel(const float* __restrict__ W, unsigned short* __restrict__ Wsw) {
    int idx = blockIdx.x * 256 + threadIdx.x;   // 0..32767
    int e  = idx & 7;
    int col = (idx >> 3) & 127;
    int kk = (idx >> 10) & 3;
    int ks = idx >> 12;
    int k = ks * 32 + kk * 8 + e;
    Wsw[idx] = bf16b(W[k * 128 + col]);
}

// ---------- Kernel 2: pre = bf16(x @ W) via v_mfma_f32_16x16x32_bf16, no LDS ----------
__global__ void gemm_kernel(const float* __restrict__ x, const unsigned short* __restrict__ Wsw,
                            unsigned short* __restrict__ preb) {
    const int lane = threadIdx.x & 63;
    const int wave = threadIdx.x >> 6;
    const int m0 = blockIdx.x * 64 + wave * 16;
    const int l15 = lane & 15;
    const int kk = lane >> 4;

    int r = m0 + l15;
    if (r > N_NODES - 1) r = N_NODES - 1;   // clamp for load safety; stores guarded
    const float* xr = x + (long)r * F_IN;

    f32x4 acc[8];
#pragma unroll
    for (int i = 0; i < 8; ++i) acc[i] = (f32x4){0.f, 0.f, 0.f, 0.f};

#pragma unroll
    for (int ks = 0; ks < 8; ++ks) {
        float4 xa = *reinterpret_cast<const float4*>(xr + ks * 32 + kk * 8);
        float4 xb = *reinterpret_cast<const float4*>(xr + ks * 32 + kk * 8 + 4);
        short8 a;
        a[0] = (short)bf16b(xa.x); a[1] = (short)bf16b(xa.y); a[2] = (short)bf16b(xa.z); a[3] = (short)bf16b(xa.w);
        a[4] = (short)bf16b(xb.x); a[5] = (short)bf16b(xb.y); a[6] = (short)bf16b(xb.z); a[7] = (short)bf16b(xb.w);
        const short8* wv = reinterpret_cast<const short8*>(Wsw) + ((ks * 4 + kk) * 128 + l15);
#pragma unroll
        for (int nf = 0; nf < 8; ++nf) {
            short8 b = wv[nf * 16];
            acc[nf] = __builtin_amdgcn_mfma_f32_16x16x32_bf16(a, b, acc[nf], 0, 0, 0);
        }
    }

    // C/D layout: col = lane&15, row = (lane>>4)*4 + reg
    const int rbase = m0 + (lane >> 4) * 4;
#pragma unroll
    for (int nf = 0; nf < 8; ++nf) {
        int cc = nf * 16 + l15;
#pragma unroll
        for (int reg = 0; reg < 4; ++reg) {
            int rr = rbase + reg;
            if (rr < N_NODES) preb[(long)rr * F_OUT + cc] = bf16b(acc[nf][reg]);
        }
    }
}

// ---------- passA: per-(bin, block) counts (no counter atomics) + degree histogram ----------
__global__ __launch_bounds__(L1_THREADS) void passA_kernel(const int* __restrict__ row,
                                                           int* __restrict__ deg,
                                                           int* __restrict__ cnt) {
    __shared__ int h[N_BINS];
    if (threadIdx.x < N_BINS) h[threadIdx.x] = 0;
    __syncthreads();
    const int g = blockIdx.x;
    const int base = g * L1_EDGES;
    for (int i = threadIdx.x; i < L1_EDGES; i += L1_THREADS) {
        int r = __builtin_nontemporal_load(row + base + i);
        atomicAdd(&deg[r], 1);                       // 100k addresses: fine
        atomicAdd(&h[r / RPB], 1);                   // LDS
    }
    __syncthreads();
    if (threadIdx.x < N_BINS)
        cnt[threadIdx.x * L1_BLOCKS + g] = h[threadIdx.x];   // bin-major regions
}

// ---------- scan32768: exclusive scan of cnt[128][256] -> off[32769] ----------
__global__ void scan32768_kernel(const int* __restrict__ cnt, int* __restrict__ off) {
    __shared__ int tmp[1024];
    int t = threadIdx.x;                             // 1024 threads x 32 elems
    const int4* c4 = reinterpret_cast<const int4*>(cnt);
    int sum = 0;
#pragma unroll
    for (int j = 0; j < 8; ++j) {
        int4 v = c4[t * 8 + j];
        sum += v.x + v.y + v.z + v.w;
    }
    tmp[t] = sum;
    __syncthreads();
#pragma unroll
    for (int o = 1; o < 1024; o <<= 1) {
        int u = (t >= o) ? tmp[t - o] : 0;
        __syncthreads();
        tmp[t] += u;
        __syncthreads();
    }
    int base = tmp[t] - sum;                         // exclusive over threads
#pragma unroll
    for (int j = 0; j < 8; ++j) {
        int4 v = c4[t * 8 + j];
        off[t * 32 + j * 4 + 0] = base; base += v.x;
        off[t * 32 + j * 4 + 1] = base; base += v.y;
        off[t * 32 + j * 4 + 2] = base; base += v.z;
        off[t * 32 + j * 4 + 3] = base; base += v.w;
    }
    if (t == 1023) off[CNT_SIZE] = base;             // = N_EDGES
}

// ---------- passB: append to pre-reserved (bin, block) sub-regions; LDS-only cursors ----------
__global__ __launch_bounds__(L1_THREADS) void passB_kernel(const int* __restrict__ row,
                                                           const int* __restrict__ col,
                                                           const float* __restrict__ vals,
                                                           const int* __restrict__ off,
                                                           unsigned* __restrict__ packed,
                                                           unsigned short* __restrict__ valh) {
    __shared__ int cur[N_BINS];
    const int g = blockIdx.x;
    if (threadIdx.x < N_BINS) cur[threadIdx.x] = off[threadIdx.x * L1_BLOCKS + g];
    __syncthreads();
    const int base = g * L1_EDGES;
    for (int i = threadIdx.x; i < L1_EDGES; i += L1_THREADS) {
        int e = base + i;
        int r = __builtin_nontemporal_load(row + e);
        int c = __builtin_nontemporal_load(col + e);
        float v = __builtin_nontemporal_load(vals + e);
        int bin = r / RPB;
        int lr = r - bin * RPB;                      // < 782, 10 bits
        int pos = atomicAdd(&cur[bin], 1);           // LDS atomic
        packed[pos] = (unsigned)c | ((unsigned)lr << 17);
        valh[pos] = bf16b(v);
    }
}

// ---------- row_start scans ----------
__global__ void scan_block_kernel(const int* __restrict__ deg, int* __restrict__ row_start,
                                  int* __restrict__ bsums) {
    __shared__ int tmp[256];
    int t = threadIdx.x;
    int i = blockIdx.x * 256 + t;
    int d = (i < N_NODES) ? deg[i] : 0;
    tmp[t] = d;
    __syncthreads();
#pragma unroll
    for (int o = 1; o < 256; o <<= 1) {
        int v = (t >= o) ? tmp[t - o] : 0;
        __syncthreads();
        tmp[t] += v;
        __syncthreads();
    }
    if (i < N_NODES) row_start[i] = tmp[t] - d;
    if (t == 255) bsums[blockIdx.x] = tmp[255];
}

__global__ void scan_bsums_kernel(int* __restrict__ bsums) {
    __shared__ int tmp[512];
    int t = threadIdx.x;
    int v = (t < SCAN_BLOCKS) ? bsums[t] : 0;
    tmp[t] = v;
    __syncthreads();
#pragma unroll
    for (int o = 1; o < 512; o <<= 1) {
        int u = (t >= o) ? tmp[t - o] : 0;
        __syncthreads();
        tmp[t] += u;
        __syncthreads();
    }
    bsums[t] = tmp[t] - v;
}

__global__ void scan_add_kernel(int* __restrict__ row_start, const int* __restrict__ bsums) {
    int i = blockIdx.x * 256 + threadIdx.x;
    if (i < N_NODES) {
        row_start[i] = row_start[i] + bsums[blockIdx.x];
        if (i == N_NODES - 1) row_start[N_NODES] = N_EDGES;
    }
}

// ---------- csr_place: ONE block per bin; LDS row-cursors; single-CU region ownership ----------
// Block b owns bin b: reads its contiguous ~100KB binned slice (NT), scatters into
// its ~100KB CSR window. Writers on ONE CU -> one XCD L2, dirty lines fill fully.
__global__ __launch_bounds__(1024) void csr_place_kernel(const unsigned* __restrict__ packed,
                                                         const unsigned short* __restrict__ valh,
                                                         const int* __restrict__ off,
                                                         const int* __restrict__ row_start,
                                                         uint2v* __restrict__ edges) {
    __shared__ int cur[RPB];
    const int b = blockIdx.x;
    const int rbase = b * RPB;
    const int nrows = min(RPB, N_NODES - rbase);
    for (int i = threadIdx.x; i < nrows; i += 1024) cur[i] = row_start[rbase + i];
    __syncthreads();
    const int lo = off[b * L1_BLOCKS];
    const int hi = off[(b + 1) * L1_BLOCKS];         // off[32768] = N_EDGES for b=127
    for (int i = lo + (int)threadIdx.x; i < hi; i += 1024) {
        unsigned p = __builtin_nontemporal_load(packed + i);
        unsigned short vh = __builtin_nontemporal_load(valh + i);
        int lr = (int)(p >> 17);
        int c = (int)(p & 0x1FFFFu);
        int pos = atomicAdd(&cur[lr], 1);            // LDS atomic
        edges[pos] = (uint2v){(unsigned)c, ((unsigned)vh) << 16};
    }
}

// ---------- spmm: readlane edge broadcast + 8-deep unconditional gather MLP ----------
__global__ __launch_bounds__(256) void spmm_csr_kernel(
    const unsigned short* __restrict__ preb, const int* __restrict__ row_start,
    const uint2v* __restrict__ edges, const float* __restrict__ bias,
    float* __restrict__ out) {
    const int lane = threadIdx.x & 63;
    const int r = blockIdx.x * 4 + (threadIdx.x >> 6);
    const int s = row_start[r];
    const int t = row_start[r + 1];
    const int n = t - s;
    float a0 = 0.f, a1 = 0.f;

    // One coalesced load grabs up to 64 edges of this row; padded lanes carry
    // {col=0, val=0} so the inner loop needs no bounds checks (0-contribution).
    uint2v ev = (uint2v){0u, 0u};
    if (lane < n) ev = edges[s + lane];
    const int nn = n < 64 ? n : 64;
    for (int j0 = 0; j0 < nn; j0 += 8) {
#pragma unroll
        for (int jj = 0; jj < 8; ++jj) {
            int j = j0 + jj;
            unsigned c = (unsigned)__builtin_amdgcn_readlane((int)ev.x, j);
            unsigned vb = (unsigned)__builtin_amdgcn_readlane((int)ev.y, j);
            unsigned g = *reinterpret_cast<const unsigned*>(preb + (size_t)c * F_OUT + lane * 2);
            float v = __uint_as_float(vb);
            a0 += v * __uint_as_float(g << 16);
            a1 += v * __uint_as_float(g & 0xFFFF0000u);
        }
    }
    // Rare n > 64 fallback (cached broadcast loads).
    for (int e = s + 64; e < t; ++e) {
        uint2v cv = edges[e];
        float v = __uint_as_float(cv.y);
        unsigned g = *reinterpret_cast<const unsigned*>(preb + (size_t)cv.x * F_OUT + lane * 2);
        a0 += v * __uint_as_float(g << 16);
        a1 += v * __uint_as_float(g & 0xFFFF0000u);
    }

    float2 bb = *reinterpret_cast<const float2*>(bias + lane * 2);
    f32x2 o;
    o.x = fmaxf(a0 + bb.x, 0.f);
    o.y = fmaxf(a1 + bb.y, 0.f);
    __builtin_nontemporal_store(o, reinterpret_cast<f32x2*>(out + (size_t)r * F_OUT + lane * 2));
}

extern "C" void kernel_launch(void* const* d_in, const int* in_sizes, int n_in,
                              void* d_out, int out_size, void* d_ws, size_t ws_size,
                              hipStream_t stream) {
    const float* x    = (const float*)d_in[0];
    const float* W    = (const float*)d_in[1];
    const float* b    = (const float*)d_in[2];
    const float* vals = (const float*)d_in[3];
    const int*   row  = (const int*)d_in[4];
    const int*   col  = (const int*)d_in[5];
    float* out = (float*)d_out;

    // Workspace layout, total 49,531,904 B (<= 51,265,536 proven available in R1):
    char* ws = (char*)d_ws;
    unsigned short* preb      = (unsigned short*)(ws);                 // 25,600,000
    unsigned short* Wsw       = (unsigned short*)(ws + 25600000);      //     65,536
    int*            row_start = (int*)(ws + 25665536);                 //    400,016
    int*            deg       = (int*)(ws + 26065568);                 //    400,000
    int*            bsums     = (int*)(ws + 26465568);                 //      4,096
    int*            cnt       = (int*)(ws + 26469664);                 //    131,072 (16B-aligned)
    int*            off       = (int*)(ws + 26600736);                 //    131,076 (+pad)
    unsigned*       packed    = (unsigned*)(ws + 26731904);            //  6,400,000
    unsigned short* valh      = (unsigned short*)(ws + 33131904);      //  3,200,000
    uint2v*         edges     = (uint2v*)(ws + 36331904);              // 12,800,000 (8B-aligned)

    // Zero deg; everything else is fully overwritten each call.
    (void)hipMemsetAsync(deg, 0, 400000, stream);

    wprep_kernel<<<128, 256, 0, stream>>>(W, Wsw);
    gemm_kernel<<<(N_NODES + 63) / 64, 256, 0, stream>>>(x, Wsw, preb);

    passA_kernel<<<L1_BLOCKS, L1_THREADS, 0, stream>>>(row, deg, cnt);
    scan32768_kernel<<<1, 1024, 0, stream>>>(cnt, off);
    passB_kernel<<<L1_BLOCKS, L1_THREADS, 0, stream>>>(row, col, vals, off, packed, valh);

    scan_block_kernel<<<SCAN_BLOCKS, 256, 0, stream>>>(deg, row_start, bsums);
    scan_bsums_kernel<<<1, 512, 0, stream>>>(bsums);
    scan_add_kernel<<<SCAN_BLOCKS, 256, 0, stream>>>(row_start, bsums);

    csr_place_kernel<<<N_BINS, 1024, 0, stream>>>(packed, valh, off, row_start, edges);

    spmm_csr_kernel<<<N_NODES / 4, 256, 0, stream>>>(preb, row_start, edges, b, out);
}

// Round 9
// 175.608 us; speedup vs baseline: 5.3520x; 1.3244x over previous
//
#include <hip/hip_runtime.h>
#include <hip/hip_bf16.h>

#define N_NODES 100000
#define N_EDGES 1600000
#define F_IN 256
#define F_OUT 128
#define SCAN_BLOCKS ((N_NODES + 255) / 256)   // 391

#define N_BINS 128
#define RPB 782                  // rows per bin: 128*782 = 100096 >= 100000
#define L1_BLOCKS 256
#define L1_THREADS 512
#define L1_EDGES (N_EDGES / L1_BLOCKS)   // 6250 exactly
#define CNT_SIZE (N_BINS * L1_BLOCKS)    // 32768

typedef __attribute__((ext_vector_type(8))) short short8;
typedef __attribute__((ext_vector_type(4))) float f32x4;
typedef __attribute__((ext_vector_type(2))) float f32x2;
typedef __attribute__((ext_vector_type(2))) unsigned int uint2v;

static __device__ __forceinline__ unsigned short bf16b(float f) {
    __hip_bfloat16 h = __float2bfloat16(f);
    return *reinterpret_cast<unsigned short*>(&h);
}

// ---------- Kernel 1: pack W [256][128] f32 -> bf16 [ks(8)][kk(4)][col(128)][e(8)] ----------
__global__ void wprep_kernel(const float* __restrict__ W, unsigned short* __restrict__ Wsw) {
    int idx = blockIdx.x * 256 + threadIdx.x;   // 0..32767
    int e  = idx & 7;
    int col = (idx >> 3) & 127;
    int kk = (idx >> 10) & 3;
    int ks = idx >> 12;
    int k = ks * 32 + kk * 8 + e;
    Wsw[idx] = bf16b(W[k * 128 + col]);
}

// ---------- Kernel 2: pre = bf16(x @ W) via v_mfma_f32_16x16x32_bf16, no LDS ----------
__global__ void gemm_kernel(const float* __restrict__ x, const unsigned short* __restrict__ Wsw,
                            unsigned short* __restrict__ preb) {
    const int lane = threadIdx.x & 63;
    const int wave = threadIdx.x >> 6;
    const int m0 = blockIdx.x * 64 + wave * 16;
    const int l15 = lane & 15;
    const int kk = lane >> 4;

    int r = m0 + l15;
    if (r > N_NODES - 1) r = N_NODES - 1;   // clamp for load safety; stores guarded
    const float* xr = x + (long)r * F_IN;

    f32x4 acc[8];
#pragma unroll
    for (int i = 0; i < 8; ++i) acc[i] = (f32x4){0.f, 0.f, 0.f, 0.f};

#pragma unroll
    for (int ks = 0; ks < 8; ++ks) {
        float4 xa = *reinterpret_cast<const float4*>(xr + ks * 32 + kk * 8);
        float4 xb = *reinterpret_cast<const float4*>(xr + ks * 32 + kk * 8 + 4);
        short8 a;
        a[0] = (short)bf16b(xa.x); a[1] = (short)bf16b(xa.y); a[2] = (short)bf16b(xa.z); a[3] = (short)bf16b(xa.w);
        a[4] = (short)bf16b(xb.x); a[5] = (short)bf16b(xb.y); a[6] = (short)bf16b(xb.z); a[7] = (short)bf16b(xb.w);
        const short8* wv = reinterpret_cast<const short8*>(Wsw) + ((ks * 4 + kk) * 128 + l15);
#pragma unroll
        for (int nf = 0; nf < 8; ++nf) {
            short8 b = wv[nf * 16];
            acc[nf] = __builtin_amdgcn_mfma_f32_16x16x32_bf16(a, b, acc[nf], 0, 0, 0);
        }
    }

    // C/D layout: col = lane&15, row = (lane>>4)*4 + reg
    const int rbase = m0 + (lane >> 4) * 4;
#pragma unroll
    for (int nf = 0; nf < 8; ++nf) {
        int cc = nf * 16 + l15;
#pragma unroll
        for (int reg = 0; reg < 4; ++reg) {
            int rr = rbase + reg;
            if (rr < N_NODES) preb[(long)rr * F_OUT + cc] = bf16b(acc[nf][reg]);
        }
    }
}

// ---------- passA: per-(bin, block) counts — NO global atomics at all ----------
__global__ __launch_bounds__(L1_THREADS) void passA_kernel(const int* __restrict__ row,
                                                           int* __restrict__ cnt) {
    __shared__ int h[N_BINS];
    if (threadIdx.x < N_BINS) h[threadIdx.x] = 0;
    __syncthreads();
    const int g = blockIdx.x;
    const int base = g * L1_EDGES;
    for (int i = threadIdx.x; i < L1_EDGES; i += L1_THREADS) {
        int r = __builtin_nontemporal_load(row + base + i);
        atomicAdd(&h[r / RPB], 1);                   // LDS only
    }
    __syncthreads();
    if (threadIdx.x < N_BINS)
        cnt[threadIdx.x * L1_BLOCKS + g] = h[threadIdx.x];   // bin-major regions
}

// ---------- scan32768: exclusive scan of cnt[128][256] -> off[32769] ----------
__global__ void scan32768_kernel(const int* __restrict__ cnt, int* __restrict__ off) {
    __shared__ int tmp[1024];
    int t = threadIdx.x;                             // 1024 threads x 32 elems
    const int4* c4 = reinterpret_cast<const int4*>(cnt);
    int sum = 0;
#pragma unroll
    for (int j = 0; j < 8; ++j) {
        int4 v = c4[t * 8 + j];
        sum += v.x + v.y + v.z + v.w;
    }
    tmp[t] = sum;
    __syncthreads();
#pragma unroll
    for (int o = 1; o < 1024; o <<= 1) {
        int u = (t >= o) ? tmp[t - o] : 0;
        __syncthreads();
        tmp[t] += u;
        __syncthreads();
    }
    int base = tmp[t] - sum;                         // exclusive over threads
#pragma unroll
    for (int j = 0; j < 8; ++j) {
        int4 v = c4[t * 8 + j];
        off[t * 32 + j * 4 + 0] = base; base += v.x;
        off[t * 32 + j * 4 + 1] = base; base += v.y;
        off[t * 32 + j * 4 + 2] = base; base += v.z;
        off[t * 32 + j * 4 + 3] = base; base += v.w;
    }
    if (t == 1023) off[CNT_SIZE] = base;             // = N_EDGES
}

// ---------- passB: append to pre-reserved (bin, block) sub-regions; LDS-only cursors ----------
__global__ __launch_bounds__(L1_THREADS) void passB_kernel(const int* __restrict__ row,
                                                           const int* __restrict__ col,
                                                           const float* __restrict__ vals,
                                                           const int* __restrict__ off,
                                                           unsigned* __restrict__ packed,
                                                           unsigned short* __restrict__ valh) {
    __shared__ int cur[N_BINS];
    const int g = blockIdx.x;
    if (threadIdx.x < N_BINS) cur[threadIdx.x] = off[threadIdx.x * L1_BLOCKS + g];
    __syncthreads();
    const int base = g * L1_EDGES;
    for (int i = threadIdx.x; i < L1_EDGES; i += L1_THREADS) {
        int e = base + i;
        int r = __builtin_nontemporal_load(row + e);
        int c = __builtin_nontemporal_load(col + e);
        float v = __builtin_nontemporal_load(vals + e);
        int bin = r / RPB;
        int lr = r - bin * RPB;                      // < 782, 10 bits
        int pos = atomicAdd(&cur[bin], 1);           // LDS atomic
        packed[pos] = (unsigned)c | ((unsigned)lr << 17);
        valh[pos] = bf16b(v);
    }
}

// ---------- bin_deg: per-bin degree from the binned stream; zero global atomics ----------
// Block b owns bin b: 782 LDS counters, streams its own contiguous slice (NT),
// writes deg[rbase..rbase+nrows) with plain coalesced stores (sole owner).
__global__ __launch_bounds__(1024) void bin_deg_kernel(const unsigned* __restrict__ packed,
                                                       const int* __restrict__ off,
                                                       int* __restrict__ deg) {
    __shared__ int h[RPB];
    const int b = blockIdx.x;
    const int rbase = b * RPB;
    const int nrows = min(RPB, N_NODES - rbase);
    for (int i = threadIdx.x; i < nrows; i += 1024) h[i] = 0;
    __syncthreads();
    const int lo = off[b * L1_BLOCKS];
    const int hi = off[(b + 1) * L1_BLOCKS];
    for (int i = lo + (int)threadIdx.x; i < hi; i += 1024) {
        unsigned p = __builtin_nontemporal_load(packed + i);
        atomicAdd(&h[p >> 17], 1);                   // LDS atomic
    }
    __syncthreads();
    for (int i = threadIdx.x; i < nrows; i += 1024) deg[rbase + i] = h[i];
}

// ---------- row_start scans ----------
__global__ void scan_block_kernel(const int* __restrict__ deg, int* __restrict__ row_start,
                                  int* __restrict__ bsums) {
    __shared__ int tmp[256];
    int t = threadIdx.x;
    int i = blockIdx.x * 256 + t;
    int d = (i < N_NODES) ? deg[i] : 0;
    tmp[t] = d;
    __syncthreads();
#pragma unroll
    for (int o = 1; o < 256; o <<= 1) {
        int v = (t >= o) ? tmp[t - o] : 0;
        __syncthreads();
        tmp[t] += v;
        __syncthreads();
    }
    if (i < N_NODES) row_start[i] = tmp[t] - d;
    if (t == 255) bsums[blockIdx.x] = tmp[255];
}

__global__ void scan_bsums_kernel(int* __restrict__ bsums) {
    __shared__ int tmp[512];
    int t = threadIdx.x;
    int v = (t < SCAN_BLOCKS) ? bsums[t] : 0;
    tmp[t] = v;
    __syncthreads();
#pragma unroll
    for (int o = 1; o < 512; o <<= 1) {
        int u = (t >= o) ? tmp[t - o] : 0;
        __syncthreads();
        tmp[t] += u;
        __syncthreads();
    }
    bsums[t] = tmp[t] - v;
}

__global__ void scan_add_kernel(int* __restrict__ row_start, const int* __restrict__ bsums) {
    int i = blockIdx.x * 256 + threadIdx.x;
    if (i < N_NODES) {
        row_start[i] = row_start[i] + bsums[blockIdx.x];
        if (i == N_NODES - 1) row_start[N_NODES] = N_EDGES;
    }
}

// ---------- csr_place: ONE block per bin; LDS row-cursors; single-CU region ownership ----------
__global__ __launch_bounds__(1024) void csr_place_kernel(const unsigned* __restrict__ packed,
                                                         const unsigned short* __restrict__ valh,
                                                         const int* __restrict__ off,
                                                         const int* __restrict__ row_start,
                                                         uint2v* __restrict__ edges) {
    __shared__ int cur[RPB];
    const int b = blockIdx.x;
    const int rbase = b * RPB;
    const int nrows = min(RPB, N_NODES - rbase);
    for (int i = threadIdx.x; i < nrows; i += 1024) cur[i] = row_start[rbase + i];
    __syncthreads();
    const int lo = off[b * L1_BLOCKS];
    const int hi = off[(b + 1) * L1_BLOCKS];         // off[32768] = N_EDGES for b=127
    for (int i = lo + (int)threadIdx.x; i < hi; i += 1024) {
        unsigned p = __builtin_nontemporal_load(packed + i);
        unsigned short vh = __builtin_nontemporal_load(valh + i);
        int lr = (int)(p >> 17);
        int c = (int)(p & 0x1FFFFu);
        int pos = atomicAdd(&cur[lr], 1);            // LDS atomic
        edges[pos] = (uint2v){(unsigned)c, ((unsigned)vh) << 16};
    }
}

// ---------- spmm: readlane edge broadcast + 8-deep unconditional gather MLP ----------
__global__ __launch_bounds__(256) void spmm_csr_kernel(
    const unsigned short* __restrict__ preb, const int* __restrict__ row_start,
    const uint2v* __restrict__ edges, const float* __restrict__ bias,
    float* __restrict__ out) {
    const int lane = threadIdx.x & 63;
    const int r = blockIdx.x * 4 + (threadIdx.x >> 6);
    const int s = row_start[r];
    const int t = row_start[r + 1];
    const int n = t - s;
    float a0 = 0.f, a1 = 0.f;

    // One coalesced load grabs up to 64 edges of this row; padded lanes carry
    // {col=0, val=0} so the inner loop needs no bounds checks (0-contribution).
    uint2v ev = (uint2v){0u, 0u};
    if (lane < n) ev = edges[s + lane];
    const int nn = n < 64 ? n : 64;
    for (int j0 = 0; j0 < nn; j0 += 8) {
#pragma unroll
        for (int jj = 0; jj < 8; ++jj) {
            int j = j0 + jj;
            unsigned c = (unsigned)__builtin_amdgcn_readlane((int)ev.x, j);
            unsigned vb = (unsigned)__builtin_amdgcn_readlane((int)ev.y, j);
            unsigned g = *reinterpret_cast<const unsigned*>(preb + (size_t)c * F_OUT + lane * 2);
            float v = __uint_as_float(vb);
            a0 += v * __uint_as_float(g << 16);
            a1 += v * __uint_as_float(g & 0xFFFF0000u);
        }
    }
    // Rare n > 64 fallback (cached broadcast loads).
    for (int e = s + 64; e < t; ++e) {
        uint2v cv = edges[e];
        float v = __uint_as_float(cv.y);
        unsigned g = *reinterpret_cast<const unsigned*>(preb + (size_t)cv.x * F_OUT + lane * 2);
        a0 += v * __uint_as_float(g << 16);
        a1 += v * __uint_as_float(g & 0xFFFF0000u);
    }

    float2 bb = *reinterpret_cast<const float2*>(bias + lane * 2);
    f32x2 o;
    o.x = fmaxf(a0 + bb.x, 0.f);
    o.y = fmaxf(a1 + bb.y, 0.f);
    __builtin_nontemporal_store(o, reinterpret_cast<f32x2*>(out + (size_t)r * F_OUT + lane * 2));
}

extern "C" void kernel_launch(void* const* d_in, const int* in_sizes, int n_in,
                              void* d_out, int out_size, void* d_ws, size_t ws_size,
                              hipStream_t stream) {
    const float* x    = (const float*)d_in[0];
    const float* W    = (const float*)d_in[1];
    const float* b    = (const float*)d_in[2];
    const float* vals = (const float*)d_in[3];
    const int*   row  = (const int*)d_in[4];
    const int*   col  = (const int*)d_in[5];
    float* out = (float*)d_out;

    // Workspace layout, total 49,531,904 B (<= 51,265,536 proven available in R1):
    char* ws = (char*)d_ws;
    unsigned short* preb      = (unsigned short*)(ws);                 // 25,600,000
    unsigned short* Wsw       = (unsigned short*)(ws + 25600000);      //     65,536
    int*            row_start = (int*)(ws + 25665536);                 //    400,016
    int*            deg       = (int*)(ws + 26065568);                 //    400,000
    int*            bsums     = (int*)(ws + 26465568);                 //      4,096
    int*            cnt       = (int*)(ws + 26469664);                 //    131,072 (16B-aligned)
    int*            off       = (int*)(ws + 26600736);                 //    131,076 (+pad)
    unsigned*       packed    = (unsigned*)(ws + 26731904);            //  6,400,000
    unsigned short* valh      = (unsigned short*)(ws + 33131904);      //  3,200,000
    uint2v*         edges     = (uint2v*)(ws + 36331904);              // 12,800,000 (8B-aligned)

    wprep_kernel<<<128, 256, 0, stream>>>(W, Wsw);
    gemm_kernel<<<(N_NODES + 63) / 64, 256, 0, stream>>>(x, Wsw, preb);

    passA_kernel<<<L1_BLOCKS, L1_THREADS, 0, stream>>>(row, cnt);
    scan32768_kernel<<<1, 1024, 0, stream>>>(cnt, off);
    passB_kernel<<<L1_BLOCKS, L1_THREADS, 0, stream>>>(row, col, vals, off, packed, valh);

    bin_deg_kernel<<<N_BINS, 1024, 0, stream>>>(packed, off, deg);
    scan_block_kernel<<<SCAN_BLOCKS, 256, 0, stream>>>(deg, row_start, bsums);
    scan_bsums_kernel<<<1, 512, 0, stream>>>(bsums);
    scan_add_kernel<<<SCAN_BLOCKS, 256, 0, stream>>>(row_start, bsums);

    csr_place_kernel<<<N_BINS, 1024, 0, stream>>>(packed, valh, off, row_start, edges);

    spmm_csr_kernel<<<N_NODES / 4, 256, 0, stream>>>(preb, row_start, edges, b, out);
}